// Round 1
// baseline (29009.012 us; speedup 1.0000x reference)
//
#include <hip/hip_runtime.h>
#include <math.h>

#define B_ 16
#define T_ 512
#define E_ 2048
#define H_ 1024
#define D_ 128
#define G_SCAN 64            // persistent workgroups for the scan (co-resident: 64 <= 256 CUs)
#define ROWS_PER_WG 16       // H_/G_SCAN

// ---------------- ws layout ----------------
// [0,     256)   : flags[G_SCAN] (int)      -- zeroed each launch
// [4096,  12288) : hbuf[2][H_] (float)      -- zeroed each launch (h0 = 0)
// [16384, 81920) : hs[B_][H_] (float)       -- fully written by scan
// [81920, +32MB) : xW[B_*T_][H_] (float)

// ================= Kernel 1: xW = x @ W_ih^T + (b_ih + b_hh) =================
// M=8192, K=2048, N=1024.  C[m][n] = sum_k x[m][k] * Wih[n][k] + bias[n]
__global__ __launch_bounds__(256) void gemm_xw(
    const float* __restrict__ x, const float* __restrict__ Wih,
    const float* __restrict__ bih, const float* __restrict__ bhh,
    float* __restrict__ xW)
{
    __shared__ float As[64][17];  // +1 pad: bank-conflict break
    __shared__ float Bs[64][17];
    const int tid = threadIdx.x;
    const int bx = blockIdx.x;     // n-tile 0..15
    const int by = blockIdx.y;     // m-tile 0..127
    const int tx = tid & 15;
    const int ty = tid >> 4;
    const int lrow = tid >> 2;        // 0..63
    const int lcol = (tid & 3) * 4;   // 0,4,8,12

    const float* Ag = x   + (size_t)(by * 64 + lrow) * E_ + lcol;
    const float* Bg = Wih + (size_t)(bx * 64 + lrow) * E_ + lcol;

    float acc[4][4] = {};
    for (int kt = 0; kt < E_; kt += 16) {
        float4 av = *(const float4*)(Ag + kt);
        float4 bv = *(const float4*)(Bg + kt);
        As[lrow][lcol + 0] = av.x; As[lrow][lcol + 1] = av.y;
        As[lrow][lcol + 2] = av.z; As[lrow][lcol + 3] = av.w;
        Bs[lrow][lcol + 0] = bv.x; Bs[lrow][lcol + 1] = bv.y;
        Bs[lrow][lcol + 2] = bv.z; Bs[lrow][lcol + 3] = bv.w;
        __syncthreads();
#pragma unroll
        for (int kk = 0; kk < 16; ++kk) {
            float a0 = As[ty * 4 + 0][kk], a1 = As[ty * 4 + 1][kk];
            float a2 = As[ty * 4 + 2][kk], a3 = As[ty * 4 + 3][kk];
            float b0 = Bs[tx * 4 + 0][kk], b1 = Bs[tx * 4 + 1][kk];
            float b2 = Bs[tx * 4 + 2][kk], b3 = Bs[tx * 4 + 3][kk];
            acc[0][0] += a0 * b0; acc[0][1] += a0 * b1; acc[0][2] += a0 * b2; acc[0][3] += a0 * b3;
            acc[1][0] += a1 * b0; acc[1][1] += a1 * b1; acc[1][2] += a1 * b2; acc[1][3] += a1 * b3;
            acc[2][0] += a2 * b0; acc[2][1] += a2 * b1; acc[2][2] += a2 * b2; acc[2][3] += a2 * b3;
            acc[3][0] += a3 * b0; acc[3][1] += a3 * b1; acc[3][2] += a3 * b2; acc[3][3] += a3 * b3;
        }
        __syncthreads();
    }
#pragma unroll
    for (int i = 0; i < 4; ++i) {
        const int m = by * 64 + ty * 4 + i;
#pragma unroll
        for (int j = 0; j < 4; ++j) {
            const int n = bx * 64 + tx * 4 + j;
            xW[(size_t)m * H_ + n] = acc[i][j] + bih[n] + bhh[n];
        }
    }
}

// ================= Kernel 2: persistent sequential RNN scan =================
// h_{s+1} = tanh(xW[m] + W_hh @ h_s), only for valid (b,t); h carries across rows.
// Each WG owns ROWS_PER_WG=16 rows of W_hh held in registers (64 floats/thread).
// Per-step device-wide sync: per-WG monotonic step flags, wave0 polls all 64.
__global__ __launch_bounds__(256) void rnn_scan(
    const float* __restrict__ Whh, const float* __restrict__ xW,
    const int* __restrict__ lengths,
    float* __restrict__ hbuf,   // [2][H_]
    float* __restrict__ hs,     // [B_][H_]
    int* __restrict__ flags)    // [G_SCAN]
{
    __shared__ float hsh[H_];
    const int tid = threadIdx.x;
    const int wg  = blockIdx.x;
    const int r   = tid >> 4;     // 0..15  (row within WG slice)
    const int sub = tid & 15;     // 0..15  (column-group; strided columns for bank-conflict-free LDS)
    const int row = wg * ROWS_PER_WG + r;   // global hidden index

    // Load this thread's W_hh slice into registers: columns sub, sub+16, ..., sub+16*63
    float wreg[64];
#pragma unroll
    for (int j = 0; j < 64; ++j)
        wreg[j] = Whh[(size_t)row * H_ + sub + 16 * j];

    int s = 0;  // global valid-step counter (identical across all WGs)
    for (int b = 0; b < B_; ++b) {
        const int len = lengths[b];
        for (int t = 0; t < len; ++t) {
            // ---- wait: all WGs completed step s-1 (wrote hbuf[s&1], done reading hbuf[(s+1)&1])
            if (tid < G_SCAN) {
                while (__hip_atomic_load(&flags[tid], __ATOMIC_RELAXED,
                                         __HIP_MEMORY_SCOPE_AGENT) < s) {}
            }
            __syncthreads();
            __builtin_amdgcn_fence(__ATOMIC_ACQUIRE, "agent");  // invalidate stale L1/L2

            const float* hin  = hbuf + (s & 1) * H_;
            float*       hout = hbuf + ((s + 1) & 1) * H_;

            // stage h into LDS (coalesced float4: 256 thr x 16B = 4KB)
            *(float4*)(hsh + tid * 4) = *(const float4*)(hin + tid * 4);
            __syncthreads();

            // partial dot over strided columns; banks: sub+16j -> conflict-free
            float p = 0.f;
#pragma unroll
            for (int j = 0; j < 64; ++j)
                p += wreg[j] * hsh[sub + 16 * j];
            // reduce across the 16 sub-lanes (consecutive lanes within a wave)
            p += __shfl_xor(p, 8, 64);
            p += __shfl_xor(p, 4, 64);
            p += __shfl_xor(p, 2, 64);
            p += __shfl_xor(p, 1, 64);

            if (sub == 0) {
                const int m = b * T_ + t;
                float v = tanhf(xW[(size_t)m * H_ + row] + p);
                hout[row] = v;
                if (t == len - 1) hs[(size_t)b * H_ + row] = v;  // final h of this row
            }
            __syncthreads();  // all stores issued+drained (vmcnt(0) before barrier)
            if (tid == 0) {
                __builtin_amdgcn_fence(__ATOMIC_RELEASE, "agent");  // writeback L2 for cross-XCD
                __hip_atomic_store(&flags[wg], s + 1, __ATOMIC_RELAXED,
                                   __HIP_MEMORY_SCOPE_AGENT);
            }
            ++s;
        }
    }
}

// ================= Kernel 3: out = hs @ W_l1^T + b_l1  (16x128) =================
__global__ __launch_bounds__(128) void out_gemm(
    const float* __restrict__ hs, const float* __restrict__ Wl1,
    const float* __restrict__ bl1, float* __restrict__ out)
{
    __shared__ float hshared[H_];
    const int b = blockIdx.x;
    const int d = threadIdx.x;
    for (int i = d; i < H_ / 4; i += 128)
        ((float4*)hshared)[i] = ((const float4*)(hs + (size_t)b * H_))[i];
    __syncthreads();
    float acc = 0.f;
    const float* wrow = Wl1 + (size_t)d * H_;
    for (int h = 0; h < H_; h += 4) {
        float4 w = *(const float4*)(wrow + h);
        acc += w.x * hshared[h] + w.y * hshared[h + 1]
             + w.z * hshared[h + 2] + w.w * hshared[h + 3];
    }
    out[b * D_ + d] = acc + bl1[d];
}

extern "C" void kernel_launch(void* const* d_in, const int* in_sizes, int n_in,
                              void* d_out, int out_size, void* d_ws, size_t ws_size,
                              hipStream_t stream) {
    const float* x       = (const float*)d_in[0];
    const int*   lengths = (const int*)  d_in[1];
    const float* Wih     = (const float*)d_in[2];
    const float* Whh     = (const float*)d_in[3];
    const float* bih     = (const float*)d_in[4];
    const float* bhh     = (const float*)d_in[5];
    const float* Wl1     = (const float*)d_in[6];
    const float* bl1     = (const float*)d_in[7];
    float* out = (float*)d_out;

    char* ws = (char*)d_ws;
    int*   flags = (int*)ws;
    float* hbuf  = (float*)(ws + 4096);
    float* hs    = (float*)(ws + 16384);
    float* xW    = (float*)(ws + 81920);

    // zero flags + h double-buffer (ws is re-poisoned 0xAA before every launch)
    hipMemsetAsync(ws, 0, 16384, stream);

    dim3 g1(H_ / 64, (B_ * T_) / 64);   // (16, 128)
    gemm_xw<<<g1, 256, 0, stream>>>(x, Wih, bih, bhh, xW);

    rnn_scan<<<G_SCAN, 256, 0, stream>>>(Whh, xW, lengths, hbuf, hs, flags);

    out_gemm<<<B_, D_, 0, stream>>>(hs, Wl1, bl1, out);
}

// Round 2
// 11186.213 us; speedup vs baseline: 2.5933x; 2.5933x over previous
//
#include <hip/hip_runtime.h>
#include <math.h>

#define B_ 16
#define T_ 512
#define E_ 2048
#define H_ 1024
#define D_ 128
#define G_SCAN 64            // persistent workgroups for the scan (co-resident: 64 <= 256 CUs)
#define ROWS_PER_WG 16       // H_/G_SCAN

// ---------------- ws layout ----------------
// [4096,  20480) : hbuf2[2][H_] (u64 {tag,valbits}) -- zeroed each launch (h0=0, tag=0)
// [32768, 98304) : hs[B_][H_] (float)
// [98304+, 32MB) : xW[B_*T_][H_] (float)   (actually at 81920*? see launch: 131072)

// ---- device-coherent 8B load/store (sc0 sc1: bypass non-coherent L1/L2, hit L3/mem) ----
__device__ __forceinline__ unsigned long long load_u64_cohere(const unsigned long long* p) {
    unsigned long long r;
    asm volatile("global_load_dwordx2 %0, %1, off sc0 sc1\n\t"
                 "s_waitcnt vmcnt(0)"
                 : "=v"(r) : "v"(p) : "memory");
    return r;
}
__device__ __forceinline__ void store_u64_cohere(unsigned long long* p, unsigned long long v) {
    asm volatile("global_store_dwordx2 %0, %1, off sc0 sc1"
                 :: "v"(p), "v"(v) : "memory");
}

// ================= Kernel 1: xW = x @ W_ih^T + (b_ih + b_hh) =================
__global__ __launch_bounds__(256) void gemm_xw(
    const float* __restrict__ x, const float* __restrict__ Wih,
    const float* __restrict__ bih, const float* __restrict__ bhh,
    float* __restrict__ xW)
{
    __shared__ float As[64][17];
    __shared__ float Bs[64][17];
    const int tid = threadIdx.x;
    const int bx = blockIdx.x;
    const int by = blockIdx.y;
    const int tx = tid & 15;
    const int ty = tid >> 4;
    const int lrow = tid >> 2;
    const int lcol = (tid & 3) * 4;

    const float* Ag = x   + (size_t)(by * 64 + lrow) * E_ + lcol;
    const float* Bg = Wih + (size_t)(bx * 64 + lrow) * E_ + lcol;

    float acc[4][4] = {};
    for (int kt = 0; kt < E_; kt += 16) {
        float4 av = *(const float4*)(Ag + kt);
        float4 bv = *(const float4*)(Bg + kt);
        As[lrow][lcol + 0] = av.x; As[lrow][lcol + 1] = av.y;
        As[lrow][lcol + 2] = av.z; As[lrow][lcol + 3] = av.w;
        Bs[lrow][lcol + 0] = bv.x; Bs[lrow][lcol + 1] = bv.y;
        Bs[lrow][lcol + 2] = bv.z; Bs[lrow][lcol + 3] = bv.w;
        __syncthreads();
#pragma unroll
        for (int kk = 0; kk < 16; ++kk) {
            float a0 = As[ty * 4 + 0][kk], a1 = As[ty * 4 + 1][kk];
            float a2 = As[ty * 4 + 2][kk], a3 = As[ty * 4 + 3][kk];
            float b0 = Bs[tx * 4 + 0][kk], b1 = Bs[tx * 4 + 1][kk];
            float b2 = Bs[tx * 4 + 2][kk], b3 = Bs[tx * 4 + 3][kk];
            acc[0][0] += a0 * b0; acc[0][1] += a0 * b1; acc[0][2] += a0 * b2; acc[0][3] += a0 * b3;
            acc[1][0] += a1 * b0; acc[1][1] += a1 * b1; acc[1][2] += a1 * b2; acc[1][3] += a1 * b3;
            acc[2][0] += a2 * b0; acc[2][1] += a2 * b1; acc[2][2] += a2 * b2; acc[2][3] += a2 * b3;
            acc[3][0] += a3 * b0; acc[3][1] += a3 * b1; acc[3][2] += a3 * b2; acc[3][3] += a3 * b3;
        }
        __syncthreads();
    }
#pragma unroll
    for (int i = 0; i < 4; ++i) {
        const int m = by * 64 + ty * 4 + i;
#pragma unroll
        for (int j = 0; j < 4; ++j) {
            const int n = bx * 64 + tx * 4 + j;
            xW[(size_t)m * H_ + n] = acc[i][j] + bih[n] + bhh[n];
        }
    }
}

// ================= Kernel 2: persistent sequential RNN scan =================
// Tagged-data protocol (no flags, no fences):
//   input of step s  = hbuf2[s&1][i]       must carry tag s
//   output of step s = hbuf2[(s+1)&1][i]   stored with tag s+1 (single dwordx2 sc0sc1)
// WAR with 2 buffers is safe: overwriting tag s+1 (at end of step s+2) requires having
// read ALL tags s+2, which requires every WG produced s+1, which (via the intra-WG
// __syncthreads between staging and producing) requires every WG finished reading s+1.
__global__ __launch_bounds__(256) void rnn_scan(
    const float* __restrict__ Whh, const float* __restrict__ xW,
    const int* __restrict__ lengths,
    unsigned long long* __restrict__ hbuf2,   // [2][H_] {tag<<32 | value_bits}
    float* __restrict__ hs)                   // [B_][H_]
{
    __shared__ float hsh[H_];
    const int tid = threadIdx.x;
    const int wg  = blockIdx.x;
    const int r   = tid >> 4;     // 0..15
    const int sub = tid & 15;     // 0..15
    const int row = wg * ROWS_PER_WG + r;

    float wreg[64];
#pragma unroll
    for (int j = 0; j < 64; ++j)
        wreg[j] = Whh[(size_t)row * H_ + sub + 16 * j];

    int s = 0;
    for (int b = 0; b < B_; ++b) {
        const int len = lengths[b];
        for (int t = 0; t < len; ++t) {
            // prefetch this step's xW value (producer lanes only) to hide under the poll
            float xw = 0.f;
            if (sub == 0) xw = xW[(size_t)(b * T_ + t) * H_ + row];

            // ---- consume: poll tagged slots of buffer s&1 until tag == s
            const unsigned long long* bin = hbuf2 + (size_t)(s & 1) * H_;
            const unsigned want = (unsigned)s;
#pragma unroll
            for (int k = 0; k < 4; ++k) {
                const int idx = tid * 4 + k;
                unsigned long long v;
                do { v = load_u64_cohere(bin + idx); } while ((unsigned)(v >> 32) != want);
                hsh[idx] = __uint_as_float((unsigned)v);
            }
            __syncthreads();

            // ---- compute: partial dot over strided columns (bank-conflict-free)
            float p = 0.f;
#pragma unroll
            for (int j = 0; j < 64; ++j)
                p += wreg[j] * hsh[sub + 16 * j];
            p += __shfl_xor(p, 8, 64);
            p += __shfl_xor(p, 4, 64);
            p += __shfl_xor(p, 2, 64);
            p += __shfl_xor(p, 1, 64);

            // ---- produce: single tagged 8B device-coherent store
            if (sub == 0) {
                float v = tanhf(xw + p);
                unsigned long long pk =
                    ((unsigned long long)(unsigned)(s + 1) << 32) |
                    (unsigned long long)__float_as_uint(v);
                store_u64_cohere(hbuf2 + (size_t)((s + 1) & 1) * H_ + row, pk);
                if (t == len - 1) hs[(size_t)b * H_ + row] = v;  // final h of this row
            }
            __syncthreads();   // protect hsh reuse next step
            ++s;
        }
    }
}

// ================= Kernel 3: out = hs @ W_l1^T + b_l1  (16x128) =================
__global__ __launch_bounds__(128) void out_gemm(
    const float* __restrict__ hs, const float* __restrict__ Wl1,
    const float* __restrict__ bl1, float* __restrict__ out)
{
    __shared__ float hshared[H_];
    const int b = blockIdx.x;
    const int d = threadIdx.x;
    for (int i = d; i < H_ / 4; i += 128)
        ((float4*)hshared)[i] = ((const float4*)(hs + (size_t)b * H_))[i];
    __syncthreads();
    float acc = 0.f;
    const float* wrow = Wl1 + (size_t)d * H_;
    for (int h = 0; h < H_; h += 4) {
        float4 w = *(const float4*)(wrow + h);
        acc += w.x * hshared[h] + w.y * hshared[h + 1]
             + w.z * hshared[h + 2] + w.w * hshared[h + 3];
    }
    out[b * D_ + d] = acc + bl1[d];
}

extern "C" void kernel_launch(void* const* d_in, const int* in_sizes, int n_in,
                              void* d_out, int out_size, void* d_ws, size_t ws_size,
                              hipStream_t stream) {
    const float* x       = (const float*)d_in[0];
    const int*   lengths = (const int*)  d_in[1];
    const float* Wih     = (const float*)d_in[2];
    const float* Whh     = (const float*)d_in[3];
    const float* bih     = (const float*)d_in[4];
    const float* bhh     = (const float*)d_in[5];
    const float* Wl1     = (const float*)d_in[6];
    const float* bl1     = (const float*)d_in[7];
    float* out = (float*)d_out;

    char* ws = (char*)d_ws;
    unsigned long long* hbuf2 = (unsigned long long*)(ws + 4096);   // 16 KB
    float* hs  = (float*)(ws + 32768);                              // 64 KB
    float* xW  = (float*)(ws + 131072);                             // 32 MB

    // zero hbuf2 (h0 = 0.0f with tag 0); ws is re-poisoned 0xAA before every launch
    hipMemsetAsync(ws, 0, 32768, stream);

    dim3 g1(H_ / 64, (B_ * T_) / 64);   // (16, 128)
    gemm_xw<<<g1, 256, 0, stream>>>(x, Wih, bih, bhh, xW);

    rnn_scan<<<G_SCAN, 256, 0, stream>>>(Whh, xW, lengths, hbuf2, hs);

    out_gemm<<<B_, D_, 0, stream>>>(hs, Wl1, bl1, out);
}

// Round 3
// 8905.890 us; speedup vs baseline: 3.2573x; 1.2560x over previous
//
#include <hip/hip_runtime.h>
#include <math.h>

#define B_ 16
#define T_ 512
#define E_ 2048
#define H_ 1024
#define D_ 128
#define G_SCAN 64            // persistent workgroups for the scan (co-resident: 64 <= 256 CUs)
#define ROWS_PER_WG 16       // H_/G_SCAN

// ---------------- ws layout ----------------
// [4096,  20480) : hbuf2[2][H_] (u64 {tag,valbits}) -- zeroed each launch (h0=0, tag=0)
// [32768, 98304) : hs[B_][H_] (float)
// [131072,+32MB) : xW[B_*T_][H_] (float)

// ---- device-coherent 8B store (sc0 sc1: bypass non-coherent L1/L2, hit coherence point) ----
__device__ __forceinline__ void store_u64_cohere(unsigned long long* p, unsigned long long v) {
    asm volatile("global_store_dwordx2 %0, %1, off sc0 sc1"
                 :: "v"(p), "v"(v) : "memory");
}
// ---- 4 coherent 8B loads issued back-to-back, ONE waitcnt (1 amortized round trip) ----
__device__ __forceinline__ void load4_u64_cohere(
    const unsigned long long* p0, const unsigned long long* p1,
    const unsigned long long* p2, const unsigned long long* p3,
    unsigned long long& a, unsigned long long& b,
    unsigned long long& c, unsigned long long& d) {
    asm volatile("global_load_dwordx2 %0, %4, off sc0 sc1\n\t"
                 "global_load_dwordx2 %1, %5, off sc0 sc1\n\t"
                 "global_load_dwordx2 %2, %6, off sc0 sc1\n\t"
                 "global_load_dwordx2 %3, %7, off sc0 sc1\n\t"
                 "s_waitcnt vmcnt(0)"
                 : "=&v"(a), "=&v"(b), "=&v"(c), "=&v"(d)
                 : "v"(p0), "v"(p1), "v"(p2), "v"(p3)
                 : "memory");
}

// fast tanh via v_exp_f32: tanh(x) = sign(x) * (1-e^{-2|x|})/(1+e^{-2|x|}); |err| ~1e-6
__device__ __forceinline__ float fast_tanh(float x) {
    float ax = fabsf(x);
    float e  = __expf(-2.0f * ax);
    float r  = __fdividef(1.0f - e, 1.0f + e);
    return copysignf(r, x);
}

// ================= Kernel 1: xW = x @ W_ih^T + (b_ih + b_hh) =================
__global__ __launch_bounds__(256) void gemm_xw(
    const float* __restrict__ x, const float* __restrict__ Wih,
    const float* __restrict__ bih, const float* __restrict__ bhh,
    float* __restrict__ xW)
{
    __shared__ float As[64][17];
    __shared__ float Bs[64][17];
    const int tid = threadIdx.x;
    const int bx = blockIdx.x;
    const int by = blockIdx.y;
    const int tx = tid & 15;
    const int ty = tid >> 4;
    const int lrow = tid >> 2;
    const int lcol = (tid & 3) * 4;

    const float* Ag = x   + (size_t)(by * 64 + lrow) * E_ + lcol;
    const float* Bg = Wih + (size_t)(bx * 64 + lrow) * E_ + lcol;

    float acc[4][4] = {};
    for (int kt = 0; kt < E_; kt += 16) {
        float4 av = *(const float4*)(Ag + kt);
        float4 bv = *(const float4*)(Bg + kt);
        As[lrow][lcol + 0] = av.x; As[lrow][lcol + 1] = av.y;
        As[lrow][lcol + 2] = av.z; As[lrow][lcol + 3] = av.w;
        Bs[lrow][lcol + 0] = bv.x; Bs[lrow][lcol + 1] = bv.y;
        Bs[lrow][lcol + 2] = bv.z; Bs[lrow][lcol + 3] = bv.w;
        __syncthreads();
#pragma unroll
        for (int kk = 0; kk < 16; ++kk) {
            float a0 = As[ty * 4 + 0][kk], a1 = As[ty * 4 + 1][kk];
            float a2 = As[ty * 4 + 2][kk], a3 = As[ty * 4 + 3][kk];
            float b0 = Bs[tx * 4 + 0][kk], b1 = Bs[tx * 4 + 1][kk];
            float b2 = Bs[tx * 4 + 2][kk], b3 = Bs[tx * 4 + 3][kk];
            acc[0][0] += a0 * b0; acc[0][1] += a0 * b1; acc[0][2] += a0 * b2; acc[0][3] += a0 * b3;
            acc[1][0] += a1 * b0; acc[1][1] += a1 * b1; acc[1][2] += a1 * b2; acc[1][3] += a1 * b3;
            acc[2][0] += a2 * b0; acc[2][1] += a2 * b1; acc[2][2] += a2 * b2; acc[2][3] += a2 * b3;
            acc[3][0] += a3 * b0; acc[3][1] += a3 * b1; acc[3][2] += a3 * b2; acc[3][3] += a3 * b3;
        }
        __syncthreads();
    }
#pragma unroll
    for (int i = 0; i < 4; ++i) {
        const int m = by * 64 + ty * 4 + i;
#pragma unroll
        for (int j = 0; j < 4; ++j) {
            const int n = bx * 64 + tx * 4 + j;
            xW[(size_t)m * H_ + n] = acc[i][j] + bih[n] + bhh[n];
        }
    }
}

// ================= Kernel 2: persistent sequential RNN scan =================
// Tagged-data protocol (no flags, no fences): slot i of buffer s&1 must carry tag s.
// Thread tid owns slots {tid, tid+256, tid+512, tid+768} (coalesced polls).
// LDS layout permuted: h[c] lives at hsh2[(c&15)*68 + (c>>4)] so thread (r,sub)'s
// compute reads hsh2[sub*68 + j], j=0..63 contiguously -> 16x ds_read_b128.
// Stride 68 (mod 32 banks = 4): writes 2-way aliased (free), b128 reads 2-way (free).
__global__ __launch_bounds__(256) void rnn_scan(
    const float* __restrict__ Whh, const float* __restrict__ xW,
    const int* __restrict__ lengths,
    unsigned long long* __restrict__ hbuf2,   // [2][H_] {tag<<32 | value_bits}
    float* __restrict__ hs)                   // [B_][H_]
{
    __shared__ float hsh2[16 * 68];
    const int tid = threadIdx.x;
    const int wg  = blockIdx.x;
    const int r   = tid >> 4;     // 0..15
    const int sub = tid & 15;     // 0..15
    const int row = wg * ROWS_PER_WG + r;

    float wreg[64];
#pragma unroll
    for (int j = 0; j < 64; ++j)
        wreg[j] = Whh[(size_t)row * H_ + sub + 16 * j];

    // LDS write addresses for this thread's 4 slots c = tid + 256k:
    // perm(c) = (c&15)*68 + (c>>4) = sub*68 + r + 16k
    float* wr = hsh2 + (size_t)sub * 68 + r;
    const float* hrow = hsh2 + (size_t)sub * 68;

    int s = 0;
    for (int b = 0; b < B_; ++b) {
        const int len = lengths[b];
        for (int t = 0; t < len; ++t) {
            // prefetch this step's xW value early (hidden under the poll)
            float xw = xW[(size_t)(b * T_ + t) * H_ + row];

            // ---- consume: poll 4 tagged slots (parallel issue) until all carry tag s
            const unsigned long long* bin = hbuf2 + (size_t)(s & 1) * H_;
            const unsigned want = (unsigned)s;
            unsigned long long v0, v1, v2, v3;
            for (;;) {
                load4_u64_cohere(bin + tid, bin + tid + 256, bin + tid + 512, bin + tid + 768,
                                 v0, v1, v2, v3);
                if ((((unsigned)(v0 >> 32)) == want) & (((unsigned)(v1 >> 32)) == want) &
                    (((unsigned)(v2 >> 32)) == want) & (((unsigned)(v3 >> 32)) == want))
                    break;
            }
            wr[0]  = __uint_as_float((unsigned)v0);
            wr[16] = __uint_as_float((unsigned)v1);
            wr[32] = __uint_as_float((unsigned)v2);
            wr[48] = __uint_as_float((unsigned)v3);
            __syncthreads();

            // ---- compute: 16x float4 LDS reads, 64 FMA
            float p = 0.f;
#pragma unroll
            for (int m = 0; m < 16; ++m) {
                float4 hv = *(const float4*)(hrow + 4 * m);
                p += wreg[4 * m + 0] * hv.x + wreg[4 * m + 1] * hv.y
                   + wreg[4 * m + 2] * hv.z + wreg[4 * m + 3] * hv.w;
            }
            p += __shfl_xor(p, 8, 64);
            p += __shfl_xor(p, 4, 64);
            p += __shfl_xor(p, 2, 64);
            p += __shfl_xor(p, 1, 64);

            float v = fast_tanh(xw + p);
            // ---- produce: single tagged 8B device-coherent store (lane sub==0 per row)
            if (sub == 0) {
                unsigned long long pk =
                    ((unsigned long long)(unsigned)(s + 1) << 32) |
                    (unsigned long long)__float_as_uint(v);
                store_u64_cohere(hbuf2 + (size_t)((s + 1) & 1) * H_ + row, pk);
                if (t == len - 1) hs[(size_t)b * H_ + row] = v;  // final h of this row
            }
            __syncthreads();   // all reads of hsh2 done before next step's writes
            ++s;
        }
    }
}

// ================= Kernel 3: out = hs @ W_l1^T + b_l1  (16x128) =================
__global__ __launch_bounds__(128) void out_gemm(
    const float* __restrict__ hs, const float* __restrict__ Wl1,
    const float* __restrict__ bl1, float* __restrict__ out)
{
    __shared__ float hshared[H_];
    const int b = blockIdx.x;
    const int d = threadIdx.x;
    for (int i = d; i < H_ / 4; i += 128)
        ((float4*)hshared)[i] = ((const float4*)(hs + (size_t)b * H_))[i];
    __syncthreads();
    float acc = 0.f;
    const float* wrow = Wl1 + (size_t)d * H_;
    for (int h = 0; h < H_; h += 4) {
        float4 w = *(const float4*)(wrow + h);
        acc += w.x * hshared[h] + w.y * hshared[h + 1]
             + w.z * hshared[h + 2] + w.w * hshared[h + 3];
    }
    out[b * D_ + d] = acc + bl1[d];
}

extern "C" void kernel_launch(void* const* d_in, const int* in_sizes, int n_in,
                              void* d_out, int out_size, void* d_ws, size_t ws_size,
                              hipStream_t stream) {
    const float* x       = (const float*)d_in[0];
    const int*   lengths = (const int*)  d_in[1];
    const float* Wih     = (const float*)d_in[2];
    const float* Whh     = (const float*)d_in[3];
    const float* bih     = (const float*)d_in[4];
    const float* bhh     = (const float*)d_in[5];
    const float* Wl1     = (const float*)d_in[6];
    const float* bl1     = (const float*)d_in[7];
    float* out = (float*)d_out;

    char* ws = (char*)d_ws;
    unsigned long long* hbuf2 = (unsigned long long*)(ws + 4096);   // 16 KB
    float* hs  = (float*)(ws + 32768);                              // 64 KB
    float* xW  = (float*)(ws + 131072);                             // 32 MB

    // zero hbuf2 (h0 = 0.0f with tag 0); ws is re-poisoned 0xAA before every launch
    hipMemsetAsync(ws, 0, 32768, stream);

    dim3 g1(H_ / 64, (B_ * T_) / 64);   // (16, 128)
    gemm_xw<<<g1, 256, 0, stream>>>(x, Wih, bih, bhh, xW);

    rnn_scan<<<G_SCAN, 256, 0, stream>>>(Whh, xW, lengths, hbuf2, hs);

    out_gemm<<<B_, D_, 0, stream>>>(hs, Wl1, bl1, out);
}

// Round 4
// 8295.483 us; speedup vs baseline: 3.4970x; 1.0736x over previous
//
#include <hip/hip_runtime.h>
#include <math.h>

#define B_ 16
#define T_ 512
#define E_ 2048
#define H_ 1024
#define D_ 128
#define G_SCAN 64            // persistent workgroups for the scan (co-resident: 64 <= 256 CUs)
#define ROWS_PER_WG 16       // H_/G_SCAN

// ---------------- ws layout ----------------
// [4096,  20480) : hbuf2[2][H_] (u64 {tag,valbits}) -- zeroed each launch (h0=0, tag=0)
// [32768, 98304) : hs[B_][H_] (float)
// [131072,+32MB) : xW[B_*T_][H_] (float)

// ---- device-coherent 8B store (sc0 sc1: bypass non-coherent caches to coherence point) ----
__device__ __forceinline__ void store_u64_cohere(unsigned long long* p, unsigned long long v) {
    asm volatile("global_store_dwordx2 %0, %1, off sc0 sc1"
                 :: "v"(p), "v"(v) : "memory");
}
// ---- 4 coherent 8B loads issued back-to-back, ONE waitcnt (1 amortized round trip) ----
__device__ __forceinline__ void load4_u64_cohere(
    const unsigned long long* p0, const unsigned long long* p1,
    const unsigned long long* p2, const unsigned long long* p3,
    unsigned long long& a, unsigned long long& b,
    unsigned long long& c, unsigned long long& d) {
    asm volatile("global_load_dwordx2 %0, %4, off sc0 sc1\n\t"
                 "global_load_dwordx2 %1, %5, off sc0 sc1\n\t"
                 "global_load_dwordx2 %2, %6, off sc0 sc1\n\t"
                 "global_load_dwordx2 %3, %7, off sc0 sc1\n\t"
                 "s_waitcnt vmcnt(0)"
                 : "=&v"(a), "=&v"(b), "=&v"(c), "=&v"(d)
                 : "v"(p0), "v"(p1), "v"(p2), "v"(p3)
                 : "memory");
}

// DPP butterfly add over a 16-lane row (VALU-rate, no LDS pipe).
// After xor1(quad_perm 0xB1), xor2(quad_perm 0x4E), row_half_mirror(0x141),
// row_mirror(0x140): EVERY lane of the 16-lane group holds the group sum.
template <int CTRL>
__device__ __forceinline__ float dpp_xadd(float v) {
    int vi = __float_as_int(v);
    int t  = __builtin_amdgcn_update_dpp(vi, vi, CTRL, 0xF, 0xF, true);
    return v + __int_as_float(t);
}

// fast tanh via v_exp_f32: tanh(x) = sign(x) * (1-e^{-2|x|})/(1+e^{-2|x|}); |err| ~1e-6
__device__ __forceinline__ float fast_tanh(float x) {
    float ax = fabsf(x);
    float e  = __expf(-2.0f * ax);
    float r  = __fdividef(1.0f - e, 1.0f + e);
    return copysignf(r, x);
}

// ================= Kernel 1: xW = x @ W_ih^T + (b_ih + b_hh) =================
__global__ __launch_bounds__(256) void gemm_xw(
    const float* __restrict__ x, const float* __restrict__ Wih,
    const float* __restrict__ bih, const float* __restrict__ bhh,
    float* __restrict__ xW)
{
    __shared__ float As[64][17];
    __shared__ float Bs[64][17];
    const int tid = threadIdx.x;
    const int bx = blockIdx.x;
    const int by = blockIdx.y;
    const int tx = tid & 15;
    const int ty = tid >> 4;
    const int lrow = tid >> 2;
    const int lcol = (tid & 3) * 4;

    const float* Ag = x   + (size_t)(by * 64 + lrow) * E_ + lcol;
    const float* Bg = Wih + (size_t)(bx * 64 + lrow) * E_ + lcol;

    float acc[4][4] = {};
    for (int kt = 0; kt < E_; kt += 16) {
        float4 av = *(const float4*)(Ag + kt);
        float4 bv = *(const float4*)(Bg + kt);
        As[lrow][lcol + 0] = av.x; As[lrow][lcol + 1] = av.y;
        As[lrow][lcol + 2] = av.z; As[lrow][lcol + 3] = av.w;
        Bs[lrow][lcol + 0] = bv.x; Bs[lrow][lcol + 1] = bv.y;
        Bs[lrow][lcol + 2] = bv.z; Bs[lrow][lcol + 3] = bv.w;
        __syncthreads();
#pragma unroll
        for (int kk = 0; kk < 16; ++kk) {
            float a0 = As[ty * 4 + 0][kk], a1 = As[ty * 4 + 1][kk];
            float a2 = As[ty * 4 + 2][kk], a3 = As[ty * 4 + 3][kk];
            float b0 = Bs[tx * 4 + 0][kk], b1 = Bs[tx * 4 + 1][kk];
            float b2 = Bs[tx * 4 + 2][kk], b3 = Bs[tx * 4 + 3][kk];
            acc[0][0] += a0 * b0; acc[0][1] += a0 * b1; acc[0][2] += a0 * b2; acc[0][3] += a0 * b3;
            acc[1][0] += a1 * b0; acc[1][1] += a1 * b1; acc[1][2] += a1 * b2; acc[1][3] += a1 * b3;
            acc[2][0] += a2 * b0; acc[2][1] += a2 * b1; acc[2][2] += a2 * b2; acc[2][3] += a2 * b3;
            acc[3][0] += a3 * b0; acc[3][1] += a3 * b1; acc[3][2] += a3 * b2; acc[3][3] += a3 * b3;
        }
        __syncthreads();
    }
#pragma unroll
    for (int i = 0; i < 4; ++i) {
        const int m = by * 64 + ty * 4 + i;
#pragma unroll
        for (int j = 0; j < 4; ++j) {
            const int n = bx * 64 + tx * 4 + j;
            xW[(size_t)m * H_ + n] = acc[i][j] + bih[n] + bhh[n];
        }
    }
}

// ================= Kernel 2: persistent sequential RNN scan =================
// Tagged-data protocol (no flags, no fences): slot i of buffer s&1 must carry tag s.
// Thread tid owns slots {tid, tid+256, tid+512, tid+768} (coalesced polls).
// LDS layout permuted: h[c] lives at hsh2[cur][(c&15)*68 + (c>>4)] so thread (r,sub)
// reads hsh2[cur][sub*68 + j], j=0..63 contiguously -> 16x ds_read_b128.
// ONE barrier per step: LDS is double-buffered (cur ^= 1). Safety of the single
// barrier: a thread writes buffer A at step s+2 only after passing poll(s+2), which
// requires all WGs produced s+2, hence passed barrier(s+1); and every thread enters
// barrier(s+1) only after finishing its step-s reads of buffer A. So no WAR overlap.
__global__ __launch_bounds__(256) void rnn_scan(
    const float* __restrict__ Whh, const float* __restrict__ xW,
    const int* __restrict__ lengths,
    unsigned long long* __restrict__ hbuf2,   // [2][H_] {tag<<32 | value_bits}
    float* __restrict__ hs)                   // [B_][H_]
{
    __shared__ float hsh2[2][16 * 68];
    const int tid = threadIdx.x;
    const int wg  = blockIdx.x;
    const int r   = tid >> 4;     // 0..15
    const int sub = tid & 15;     // 0..15
    const int row = wg * ROWS_PER_WG + r;

    float wreg[64];
#pragma unroll
    for (int j = 0; j < 64; ++j)
        wreg[j] = Whh[(size_t)row * H_ + sub + 16 * j];

    int s = 0, cur = 0;
    for (int b = 0; b < B_; ++b) {
        const int len = lengths[b];
        for (int t = 0; t < len; ++t) {
            // prefetch this step's xW value early (hidden under the poll)
            float xw = xW[(size_t)(b * T_ + t) * H_ + row];

            // ---- consume: poll 4 tagged slots (parallel issue) until all carry tag s
            const unsigned long long* bin = hbuf2 + (size_t)(s & 1) * H_;
            const unsigned want = (unsigned)s;
            unsigned long long v0, v1, v2, v3;
            for (;;) {
                load4_u64_cohere(bin + tid, bin + tid + 256, bin + tid + 512, bin + tid + 768,
                                 v0, v1, v2, v3);
                if ((((unsigned)(v0 >> 32)) == want) & (((unsigned)(v1 >> 32)) == want) &
                    (((unsigned)(v2 >> 32)) == want) & (((unsigned)(v3 >> 32)) == want))
                    break;
            }
            // stage into current LDS buffer: perm(c)=sub*68 + r + 16k (2-way banks = free)
            float* wr = &hsh2[cur][sub * 68 + r];
            wr[0]  = __uint_as_float((unsigned)v0);
            wr[16] = __uint_as_float((unsigned)v1);
            wr[32] = __uint_as_float((unsigned)v2);
            wr[48] = __uint_as_float((unsigned)v3);
            __syncthreads();   // the ONLY barrier this step

            // ---- compute: 16x float4 LDS reads, 64 FMA
            const float* hrow = &hsh2[cur][sub * 68];
            float p = 0.f;
#pragma unroll
            for (int m = 0; m < 16; ++m) {
                float4 hv = *(const float4*)(hrow + 4 * m);
                p += wreg[4 * m + 0] * hv.x + wreg[4 * m + 1] * hv.y
                   + wreg[4 * m + 2] * hv.z + wreg[4 * m + 3] * hv.w;
            }
            // DPP butterfly over the 16-lane group (VALU-rate; no LDS pipe)
            p = dpp_xadd<0xB1>(p);    // quad_perm [1,0,3,2]  (xor 1)
            p = dpp_xadd<0x4E>(p);    // quad_perm [2,3,0,1]  (xor 2)
            p = dpp_xadd<0x141>(p);   // row_half_mirror      (pair across quads)
            p = dpp_xadd<0x140>(p);   // row_mirror           (pair across halves)

            float v = fast_tanh(xw + p);
            // ---- produce: single tagged 8B device-coherent store (lane sub==0 per row)
            if (sub == 0) {
                unsigned long long pk =
                    ((unsigned long long)(unsigned)(s + 1) << 32) |
                    (unsigned long long)__float_as_uint(v);
                store_u64_cohere(hbuf2 + (size_t)((s + 1) & 1) * H_ + row, pk);
                if (t == len - 1) hs[(size_t)b * H_ + row] = v;  // final h of this row
            }
            cur ^= 1;
            ++s;
        }
    }
}

// ================= Kernel 3: out = hs @ W_l1^T + b_l1  (16x128) =================
__global__ __launch_bounds__(128) void out_gemm(
    const float* __restrict__ hs, const float* __restrict__ Wl1,
    const float* __restrict__ bl1, float* __restrict__ out)
{
    __shared__ float hshared[H_];
    const int b = blockIdx.x;
    const int d = threadIdx.x;
    for (int i = d; i < H_ / 4; i += 128)
        ((float4*)hshared)[i] = ((const float4*)(hs + (size_t)b * H_))[i];
    __syncthreads();
    float acc = 0.f;
    const float* wrow = Wl1 + (size_t)d * H_;
    for (int h = 0; h < H_; h += 4) {
        float4 w = *(const float4*)(wrow + h);
        acc += w.x * hshared[h] + w.y * hshared[h + 1]
             + w.z * hshared[h + 2] + w.w * hshared[h + 3];
    }
    out[b * D_ + d] = acc + bl1[d];
}

extern "C" void kernel_launch(void* const* d_in, const int* in_sizes, int n_in,
                              void* d_out, int out_size, void* d_ws, size_t ws_size,
                              hipStream_t stream) {
    const float* x       = (const float*)d_in[0];
    const int*   lengths = (const int*)  d_in[1];
    const float* Wih     = (const float*)d_in[2];
    const float* Whh     = (const float*)d_in[3];
    const float* bih     = (const float*)d_in[4];
    const float* bhh     = (const float*)d_in[5];
    const float* Wl1     = (const float*)d_in[6];
    const float* bl1     = (const float*)d_in[7];
    float* out = (float*)d_out;

    char* ws = (char*)d_ws;
    unsigned long long* hbuf2 = (unsigned long long*)(ws + 4096);   // 16 KB
    float* hs  = (float*)(ws + 32768);                              // 64 KB
    float* xW  = (float*)(ws + 131072);                             // 32 MB

    // zero hbuf2 (h0 = 0.0f with tag 0); ws is re-poisoned 0xAA before every launch
    hipMemsetAsync(ws, 0, 32768, stream);

    dim3 g1(H_ / 64, (B_ * T_) / 64);   // (16, 128)
    gemm_xw<<<g1, 256, 0, stream>>>(x, Wih, bih, bhh, xW);

    rnn_scan<<<G_SCAN, 256, 0, stream>>>(Whh, xW, lengths, hbuf2, hs);

    out_gemm<<<B_, D_, 0, stream>>>(hs, Wl1, bl1, out);
}